// Round 7
// baseline (285.475 us; speedup 1.0000x reference)
//
#include <hip/hip_runtime.h>

// R32 — bit-plane split. Evidence: fills hit 6.4 TB/s with MB-scale LINEAR
// runs; our kernel (~95us inferred component of the 266us composite; absent
// from top-5 so its dispatch <165us) gets ~2.8 TB/s with 256KB-strided
// t-plane writes. NT (R29) and 16KB runs (R31) both neutral -> only
// per-channel run length left. This round: decouple compute from write order.
//  K1: census-proven recurrence -> spike BITS (8 MiB workspace, [b][t][f/8]).
//  K2: fill-clone expander — grid-stride, dense 8 MiB contiguous window per
//      iteration (b-major), pure linear float4 stores of 1.0f/0.0f.
// Numerics identical to R25 (acc+=x; m=acc>=thr; acc=m?0:acc;
// thr=fmaf(thr,0.9f,0.1f*|x|)) — spike VALUES unchanged, only write order.
// Fallback to proven R25 single kernel if ws_size < 8 MiB.

#define TSTEPS 32
#define BDIM 32
#define FDIM 65536

typedef float floatx4 __attribute__((ext_vector_type(4)));

// ---- Kernel 1: recurrence -> bitmasks (8 f per thread, 1 byte per t) ----
__global__ __launch_bounds__(256) void spike_bits_kernel(
    const float* __restrict__ x, unsigned char* __restrict__ bits) {
    int tid = blockIdx.x * blockDim.x + threadIdx.x;   // 0..262143
    int fb  = tid & 8191;                              // byte index in f (f0 = fb*8)
    int b   = tid >> 13;

    const float* xb = x + ((size_t)b << 16) + ((size_t)fb << 3);
    const floatx4 v0 = *reinterpret_cast<const floatx4*>(xb);
    const floatx4 v1 = *reinterpret_cast<const floatx4*>(xb + 4);

    float xs[8], acc[8], thr[8], ad[8];
#pragma unroll
    for (int e = 0; e < 8; ++e) {
        xs[e]  = (e < 4) ? v0[e] : v1[e - 4];
        acc[e] = 0.0f;
        thr[e] = 0.5f;
        ad[e]  = 0.1f * fabsf(xs[e]);   // one rounding (identical to R25)
    }

    unsigned char* ob = bits + (((size_t)b * TSTEPS) << 13) + fb;

#pragma unroll
    for (int t = 0; t < TSTEPS; ++t) {
        unsigned m8 = 0;
#pragma unroll
        for (int e = 0; e < 8; ++e) {
            acc[e] = acc[e] + xs[e];
            bool m = acc[e] >= thr[e];
            m8 |= (m ? 1u : 0u) << e;
            acc[e] = m ? 0.0f : acc[e];
            thr[e] = __builtin_fmaf(thr[e], 0.9f, ad[e]);   // fused, 1 rounding
        }
        ob[(size_t)t << 13] = (unsigned char)m8;   // coalesced 64B/wave runs
    }
}

// ---- Kernel 2: fill-clone expander — dense 8 MiB window per iteration ----
__global__ __launch_bounds__(256) void spike_expand_kernel(
    const unsigned char* __restrict__ bits, float* __restrict__ out) {
    int gid = blockIdx.x * blockDim.x + threadIdx.x;   // 0..524287
    int t   = gid >> 14;                               // constant per thread
    int f   = (gid << 2) & (FDIM - 1);                 // multiple of 4

    const unsigned char* bp = bits + ((size_t)t << 13) + (f >> 3);
    const int sh = f & 7;                              // 0 or 4
    float* op = out + ((size_t)gid << 2);              // t<<16 | f

#pragma unroll 8
    for (int b = 0; b < BDIM; ++b) {                   // each b: dense 8 MiB plane-set
        unsigned nib = ((unsigned)bp[(size_t)b << 18] >> sh) & 0xFu;
        floatx4 sp;
        sp.x = (nib & 1u) ? 1.0f : 0.0f;
        sp.y = (nib & 2u) ? 1.0f : 0.0f;
        sp.z = (nib & 4u) ? 1.0f : 0.0f;
        sp.w = (nib & 8u) ? 1.0f : 0.0f;
        *reinterpret_cast<floatx4*>(op + ((size_t)b << 21)) = sp;
    }
}

// ---- Fallback: proven R25 single kernel (260.3us-class) ----
__global__ __launch_bounds__(256) void spike_fma_f32_kernel(
    const float* __restrict__ x, float* __restrict__ out) {
    int gid = blockIdx.x * blockDim.x + threadIdx.x;
    int fi  = gid & (FDIM / 4 - 1);
    int b   = gid >> 14;
    int f   = fi << 2;

    const floatx4 xv = *reinterpret_cast<const floatx4*>(x + (size_t)b * FDIM + f);
    float xs[4] = {xv.x, xv.y, xv.z, xv.w};

    float acc[4], thr[4], ad[4];
#pragma unroll
    for (int i = 0; i < 4; ++i) {
        acc[i] = 0.0f; thr[i] = 0.5f; ad[i] = 0.1f * fabsf(xs[i]);
    }
    float* outb = out + (size_t)b * TSTEPS * FDIM + f;
#pragma unroll
    for (int t = 0; t < TSTEPS; ++t) {
        floatx4 sp;
#pragma unroll
        for (int e = 0; e < 4; ++e) {
            acc[e] = acc[e] + xs[e];
            bool m = acc[e] >= thr[e];
            sp[e]  = m ? 1.0f : 0.0f;
            acc[e] = m ? 0.0f : acc[e];
            thr[e] = __builtin_fmaf(thr[e], 0.9f, ad[e]);
        }
        *reinterpret_cast<floatx4*>(outb + (size_t)t * FDIM) = sp;
    }
}

extern "C" void kernel_launch(void* const* d_in, const int* in_sizes, int n_in,
                              void* d_out, int out_size, void* d_ws, size_t ws_size,
                              hipStream_t stream) {
    (void)in_sizes; (void)n_in; (void)out_size;
    const float* x = (const float*)d_in[0];
    float* out     = (float*)d_out;
    const size_t bits_bytes = (size_t)BDIM * TSTEPS * (FDIM / 8);   // 8 MiB
    if (d_ws != nullptr && ws_size >= bits_bytes) {
        unsigned char* bits = (unsigned char*)d_ws;
        spike_bits_kernel<<<BDIM * FDIM / 8 / 256, 256, 0, stream>>>(x, bits);
        spike_expand_kernel<<<BDIM * FDIM / 4 / 256, 256, 0, stream>>>(bits, out);
    } else {
        spike_fma_f32_kernel<<<BDIM * FDIM / 4 / 256, 256, 0, stream>>>(x, out);
    }
}

// Round 11
// 270.710 us; speedup vs baseline: 1.0545x; 1.0545x over previous
//
#include <hip/hip_runtime.h>

// R36 — resubmit of R33/R34/R35 (four acquisition timeouts; probe never ran).
// DIAGNOSTIC: two-pass idempotent double-write probe.
// Composite analysis: dur_us = 1GiB poison-fill (~170, drifts) + ~99us const.
// Decomp-A: kernel ~92us @2.8TB/s (no mechanism left — fill-clone K2 refuted
// pattern theories). Decomp-B: hidden 256MiB out-poison (~42us) + kernel
// ~50us @5.5TB/s (explains all neutral results; we'd be AT roofline).
// This probe doubles kernel HBM writes (same values, two temporally-separated
// passes; L2 can't merge across 256MiB). Pre-registered:
//   B: composite ~300-320 (delta +40); kernel stays <top-5 -> ROOFLINE next.
//   A: composite ~350-365 (delta +90); kernel ENTERS top-5 -> real counters.
// Recurrence identical to census-proven R25:
//   acc += x; m = acc>=thr; sp = m?1:0; acc = m?0:acc;
//   thr = fmaf(thr, 0.9f, 0.1f*|x|)   <- single rounding (matches XLA fusion)

#define TSTEPS 32
#define BDIM 32
#define FDIM 65536

typedef float floatx4 __attribute__((ext_vector_type(4)));

__global__ __launch_bounds__(256) void spike_probe2x_kernel(
    const float* __restrict__ x, float* __restrict__ out) {
    int gid = blockIdx.x * blockDim.x + threadIdx.x;   // 0 .. B*F/4-1
    int fi  = gid & (FDIM / 4 - 1);                    // 0..16383
    int b   = gid >> 14;                               // F/4 = 16384
    int f   = fi << 2;

    const floatx4 xv = *reinterpret_cast<const floatx4*>(x + (size_t)b * FDIM + f);
    float xs[4] = {xv.x, xv.y, xv.z, xv.w};

    float ad[4];
#pragma unroll
    for (int i = 0; i < 4; ++i) ad[i] = 0.1f * fabsf(xs[i]);   // one rounding

    float* outb = out + (size_t)b * TSTEPS * FDIM + f;

    for (int pass = 0; pass < 2; ++pass) {
        float acc[4], thr[4];
#pragma unroll
        for (int i = 0; i < 4; ++i) { acc[i] = 0.0f; thr[i] = 0.5f; }

#pragma unroll
        for (int t = 0; t < TSTEPS; ++t) {
            floatx4 sp;
#pragma unroll
            for (int e = 0; e < 4; ++e) {
                acc[e] = acc[e] + xs[e];
                bool m = acc[e] >= thr[e];
                sp[e]  = m ? 1.0f : 0.0f;
                acc[e] = m ? 0.0f : acc[e];
                thr[e] = __builtin_fmaf(thr[e], 0.9f, ad[e]);   // fused
            }
            *reinterpret_cast<floatx4*>(outb + (size_t)t * FDIM) = sp;
        }
        // Keep pass-1 stores alive; force temporal separation of the passes.
        asm volatile("" ::: "memory");
    }
}

extern "C" void kernel_launch(void* const* d_in, const int* in_sizes, int n_in,
                              void* d_out, int out_size, void* d_ws, size_t ws_size,
                              hipStream_t stream) {
    (void)in_sizes; (void)n_in; (void)d_ws; (void)ws_size; (void)out_size;
    const float* x = (const float*)d_in[0];
    float* out     = (float*)d_out;
    const int total_threads = BDIM * FDIM / 4;   // 524288
    spike_probe2x_kernel<<<total_threads / 256, 256, 0, stream>>>(x, out);
}